// Round 1
// baseline (101.706 us; speedup 1.0000x reference)
//
#include <hip/hip_runtime.h>
#include <hip/hip_fp16.h>

// Problem constants (fixed by reference setup_inputs)
#define B_    4
#define C_    128
#define H_    64
#define W_    64
#define CO_   128
#define K_    9
#define DG_   2
#define HW_   4096
#define CK_   1152
#define NKT_  36        // CK_/32
#define NPAIR_ 576      // CK_/2
#define XSTR_ 68        // LDS plane row stride in h4v elements (8B): bank-rotating

typedef __attribute__((ext_vector_type(8))) short    short8;
typedef __attribute__((ext_vector_type(4))) float    floatx4;
typedef __attribute__((ext_vector_type(4))) _Float16 h4v;    // 8B, one pixel x 4 channels

// Static staging buffers, fully rewritten every launch.
// K-dimension is reordered k-major: ck' = k*128 + c (A and B agree; GEMM is
// order-invariant). A in MFMA-fragment order: [kt][mt(co16)][lane][8k'].
__device__ __align__(16) unsigned short g_wA[NKT_ * 8 * 64 * 8];
// col 64-pixel-tile-blocked pair-interleaved: [b][pt64][pair'][pl64] uints,
// pair' = k*64 + c/2, dword = {bf16 ck'=2p, bf16 ck'=2p+1} (channels 2c,2c+1).
__device__ __align__(16) unsigned int   g_colu[(size_t)B_ * 64 * NPAIR_ * 64];
__device__ __align__(16) int4           g_desc[B_ * DG_ * K_ * HW_];   // {padded base, h2(w00,w01), h2(w10,w11), 0}

__device__ __forceinline__ unsigned short f32_to_bf16(float f) {
    unsigned int u = __float_as_uint(f);
    u += 0x7FFFu + ((u >> 16) & 1u);           // round-to-nearest-even
    return (unsigned short)(u >> 16);
}
__device__ __forceinline__ unsigned int pack_bf16x2(float a, float b) {
    return (unsigned int)f32_to_bf16(a) | ((unsigned int)f32_to_bf16(b) << 16);
}

// ---- Kernel 1: weight -> bf16 A-fragment layout (k-major) + descriptors ----
__global__ __launch_bounds__(256) void prep_kernel(
    const float* __restrict__ w,
    const float* __restrict__ offset,
    const float* __restrict__ mask)
{
    const int bid = blockIdx.x;
    if (bid < 576) {
        // weights: 147456 elements into fragment order, k-major ck'
        const int lin  = bid * 256 + threadIdx.x;
        const int j    = lin & 7;
        const int lane = (lin >> 3) & 63;
        const int mtkt = lin >> 9;             // kt*8 + mt
        const int mt   = mtkt & 7;
        const int kt   = mtkt >> 3;
        const int co   = mt * 16 + (lane & 15);
        const int kp   = kt * 32 + (lane >> 4) * 8 + j;   // ck' = k*128 + c
        const int c    = kp & 127;
        const int k    = kp >> 7;
        g_wA[lin] = f32_to_bf16(w[co * CK_ + c * 9 + k]);
    } else {
        // descriptors: 294912 = 72 bgk * 4096 pix
        const int lin = (bid - 576) * 256 + threadIdx.x;
        const int pix = lin & (HW_ - 1);
        const int bgk = lin >> 12;             // (b*2+g)*9 + k
        const int k   = bgk % 9;
        const int bg  = bgk / 9;
        const int ho = pix >> 6;
        const int wo = pix & 63;
        const int ky = k / 3;
        const int kx = k - 3 * ky;

        const float py = offset[(size_t)(bg * 18 + 2 * k)     * HW_ + pix] + (float)(ho - 1 + ky);
        const float px = offset[(size_t)(bg * 18 + 2 * k + 1) * HW_ + pix] + (float)(wo - 1 + kx);
        const float m  = mask  [(size_t)(bg * 9 + k)          * HW_ + pix];

        const float y0f = floorf(py);
        const float x0f = floorf(px);
        const float ly = py - y0f;
        const float lx = px - x0f;
        const int y0 = (int)y0f;
        const int x0 = (int)x0f;

        // clamped 2x2 load window + folded edge weights
        const bool yin = (y0 >= 0) & (y0 <= H_ - 2);
        const float er0 = yin ? (1.0f - ly) : ((y0 == -1)     ? ly          : 0.0f);
        const float er1 = yin ? ly          : ((y0 == H_ - 1) ? (1.0f - ly) : 0.0f);
        const bool xin = (x0 >= 0) & (x0 <= W_ - 2);
        const float ec0 = xin ? (1.0f - lx) : ((x0 == -1)     ? lx          : 0.0f);
        const float ec1 = xin ? lx          : ((x0 == W_ - 1) ? (1.0f - lx) : 0.0f);
        const int yc = min(max(y0, 0), H_ - 2);
        const int xc = min(max(x0, 0), W_ - 2);

        const __half2 wlo = __floats2half2_rn(m * er0 * ec0, m * er0 * ec1);
        const __half2 whi = __floats2half2_rn(m * er1 * ec0, m * er1 * ec1);
        int4 d;
        d.x = yc * XSTR_ + xc;                 // padded-plane ELEMENT base
        d.y = __builtin_bit_cast(int, wlo);
        d.z = __builtin_bit_cast(int, whi);
        d.w = 0;
        g_desc[lin] = d;
    }
}

// ---- Kernel 2 (hot): col from 4-channel-interleaved fp16 LDS planes. ----
// Block = (b, channel-quad, pixel-quarter): 512 blocks x 1024 thr.
// Tap-row read = ds_read2_b64 -> (x,x+1) x 4 channels; per-k compute+store
// (k-major pairs are channel-contiguous) keeps VGPR low -> 2 blocks/CU.
// XCD-chunked block swizzle: HW round-robins consecutive blockIdx across the
// 8 XCDs; remap so each XCD owns one (b,g) = 64 blocks (= 2/CU x 32 CU, all
// co-resident). Then every block sharing a desc slab (16 cq) AND every block
// sharing x planes (4 qu) hits the same XCD's L2: x+desc fetched from HBM
// once instead of 4x/2x.
__global__ __launch_bounds__(1024) void col_kernel(const float* __restrict__ x)
{
    const int hw  = blockIdx.x;            // 512 = 8 xcd * 64
    const int bid = (hw & 7) * 64 + (hw >> 3);
    const int b   = bid >> 7;
    const int rem = bid & 127;
    const int cq  = rem >> 2;              // channel quad 0..31
    const int qu  = rem & 3;
    const int c0  = cq * 4;
    const int g   = cq >> 4;               // deform group
    const int t   = threadIdx.x;

    __shared__ h4v s_x4[64 * XSTR_];       // 34816 B

    {   // stage 4 planes interleaved: thread t -> pixels 4t..4t+3
        const int p0  = t * 4;
        const int row = p0 >> 6;
        const int col = p0 & 63;
        const float* __restrict__ src = x + ((size_t)(b * C_ + c0) << 12) + p0;
        const float4 f0 = *(const float4*)(src);
        const float4 f1 = *(const float4*)(src + HW_);
        const float4 f2 = *(const float4*)(src + 2 * HW_);
        const float4 f3 = *(const float4*)(src + 3 * HW_);
        h4v* dst = s_x4 + row * XSTR_ + col;
        dst[0] = h4v{(_Float16)f0.x, (_Float16)f1.x, (_Float16)f2.x, (_Float16)f3.x};
        dst[1] = h4v{(_Float16)f0.y, (_Float16)f1.y, (_Float16)f2.y, (_Float16)f3.y};
        dst[2] = h4v{(_Float16)f0.z, (_Float16)f1.z, (_Float16)f2.z, (_Float16)f3.z};
        dst[3] = h4v{(_Float16)f0.w, (_Float16)f1.w, (_Float16)f2.w, (_Float16)f3.w};
    }
    __syncthreads();

    const int pix = qu * 1024 + t;
    const int pt  = pix >> 6;
    const int pl  = pix & 63;
    const int4* __restrict__ descb =
        g_desc + (size_t)((b * DG_ + g) * 9) * HW_ + pix;
    unsigned int* __restrict__ outb =
        g_colu + ((size_t)(b * 64 + pt) * NPAIR_ + 2 * cq) * 64 + pl;

#pragma unroll
    for (int k = 0; k < 9; ++k) {
        const int4 d = descb[(size_t)k * HW_];
        const float2 wl = __half22float2(__builtin_bit_cast(__half2, d.y));
        const float2 wh = __half22float2(__builtin_bit_cast(__half2, d.z));
        const h4v* p = s_x4 + d.x;
        const h4v lo0 = p[0];
        const h4v lo1 = p[1];
        const h4v hi0 = p[XSTR_];
        const h4v hi1 = p[XSTR_ + 1];
        float v[4];
#pragma unroll
        for (int ci = 0; ci < 4; ++ci)
            v[ci] = wl.x * (float)lo0[ci] + wl.y * (float)lo1[ci]
                  + wh.x * (float)hi0[ci] + wh.y * (float)hi1[ci];
        // pair' = k*64 + 2cq + {0,1}; dword = {even ck', odd ck'} = ch pairs
        outb[k * 64 * 64]      = pack_bf16x2(v[0], v[1]);
        outb[k * 64 * 64 + 64] = pack_bf16x2(v[2], v[3]);
    }
}

// ---- Kernel 3: GEMM, zero LDS, zero barriers. 256 blocks x 1024 thr. ----
// 16 waves = 4 co-ranges x 4 pixel-subtiles over a 64-pixel slab (147KB
// contiguous). A-frag = contiguous 1KB/wave b128 from g_wA; B-frag = 4
// coalesced b32 from L3-resident g_colu (~500-700cyc). Grid == #CUs so
// occupancy is pinned at 4 waves/SIMD; latency hiding must come from ILP:
// depth-3 rotating prefetch ring (was depth-1). unroll 6 keeps kt%3 static
// so the ring stays in registers (rule: no runtime-indexed reg arrays).
__global__ __launch_bounds__(1024) void gemm_kernel(
    const float* __restrict__ bias, float* __restrict__ out)
{
    const int bid  = blockIdx.x;           // 256 = 4b * 64 pt64
    const int b    = bid >> 6;
    const int pt   = bid & 63;
    const int t    = threadIdx.x;
    const int w    = t >> 6;               // wave 0..15
    const int cw   = w >> 2;               // co-range (32 co)
    const int nt   = w & 3;                // 16-pixel subtile
    const int lane = t & 63;
    const int l15  = lane & 15;
    const int quad = lane >> 4;

    // A: frag (kt, mt=cw*2+mtl) at ((kt*8+mt)*64 + lane)*8
    const unsigned short* __restrict__ ap = g_wA + ((size_t)(cw * 2) * 64 + lane) * 8;
    // B: lane reads pairs (kt*16 + quad*4 + j2) at pixel nt*16+l15
    const unsigned int* __restrict__ bp =
        g_colu + ((size_t)(b * 64 + pt) * NPAIR_ + quad * 4) * 64 + nt * 16 + l15;

    floatx4 acc0 = {0.f, 0.f, 0.f, 0.f};
    floatx4 acc1 = {0.f, 0.f, 0.f, 0.f};

    short8 a0buf[3], a1buf[3], bbuf[3];
#pragma unroll
    for (int i = 0; i < 3; ++i) {
        const unsigned short* an = ap + (size_t)i * 4096;
        a0buf[i] = *(const short8*)an;
        a1buf[i] = *(const short8*)(an + 512);
        const unsigned int* bq = bp + (size_t)i * 1024;
        uint4 u;
        u.x = bq[0]; u.y = bq[64]; u.z = bq[128]; u.w = bq[192];
        bbuf[i] = __builtin_bit_cast(short8, u);
    }

#pragma unroll 6
    for (int kt = 0; kt < NKT_; ++kt) {
        const int s = kt % 3;              // static under unroll 6
        short8 a0n, a1n, b_n;
        if (kt + 3 < NKT_) {               // issue loads for kt+3 first
            const unsigned short* an = ap + (size_t)(kt + 3) * 4096;
            a0n = *(const short8*)an;
            a1n = *(const short8*)(an + 512);
            const unsigned int* bq = bp + (size_t)(kt + 3) * 1024;
            uint4 u;
            u.x = bq[0]; u.y = bq[64]; u.z = bq[128]; u.w = bq[192];
            b_n = __builtin_bit_cast(short8, u);
        }
        acc0 = __builtin_amdgcn_mfma_f32_16x16x32_bf16(a0buf[s], bbuf[s], acc0, 0, 0, 0);
        acc1 = __builtin_amdgcn_mfma_f32_16x16x32_bf16(a1buf[s], bbuf[s], acc1, 0, 0, 0);
        if (kt + 3 < NKT_) {
            a0buf[s] = a0n; a1buf[s] = a1n; bbuf[s] = b_n;
        }
    }

    // C/D: col = l15 (pixel), row = quad*4 + r (co within 16-tile)
    const int pixo = pt * 64 + nt * 16 + l15;
#pragma unroll
    for (int mtl = 0; mtl < 2; ++mtl) {
        const floatx4 a = mtl ? acc1 : acc0;
        const int cob = cw * 32 + mtl * 16 + quad * 4;
#pragma unroll
        for (int r = 0; r < 4; ++r) {
            const int co = cob + r;
            out[((size_t)(b * CO_ + co) << 12) + pixo] = a[r] + bias[co];
        }
    }
}

extern "C" void kernel_launch(void* const* d_in, const int* in_sizes, int n_in,
                              void* d_out, int out_size, void* d_ws, size_t ws_size,
                              hipStream_t stream) {
    const float* x      = (const float*)d_in[0];
    const float* offset = (const float*)d_in[1];
    const float* mask   = (const float*)d_in[2];
    const float* weight = (const float*)d_in[3];
    const float* bias   = (const float*)d_in[4];
    float* out = (float*)d_out;

    hipLaunchKernelGGL(prep_kernel, dim3(576 + 1152), dim3(256), 0, stream, weight, offset, mask);
    hipLaunchKernelGGL(col_kernel, dim3(512), dim3(1024), 0, stream, x);
    hipLaunchKernelGGL(gemm_kernel, dim3(256), dim3(1024), 0, stream, bias, out);
}